// Round 16
// baseline (230.545 us; speedup 1.0000x reference)
//
#include <hip/hip_runtime.h>
#include <hip/hip_bf16.h>
#include <hip/hip_fp16.h>

#define N_NODES 50000
#define N_EDGES 800000
#define CH 64
#define N_GRAPHS 256
#define NBUCK 196            // ceil(50000/256); bucket = dst >> 8
#define MAXB 4608            // padded bucket capacity (mean 4096, sigma~64)
#define NPAD (NBUCK * MAXB)  // 903168 padded edge slots
#define CHUNK 2048           // edges staged per scatter block
#define SCAT_BLK ((N_EDGES + CHUNK - 1) / CHUNK)   // 391
#define GEMM_BLK ((N_NODES + 31) / 32)             // 1563

__device__ __forceinline__ unsigned bf16_rne(float f) {
    unsigned u = __float_as_uint(f);
    return (u + 0x7fffu + ((u >> 16) & 1u)) >> 16;
}
__device__ __forceinline__ float4 ldtab(const unsigned short* __restrict__ tab, int s, int c4) {
    uint2 u = *(const uint2*)(tab + ((size_t)s << 6) + c4);
    float4 r;
    r.x = __uint_as_float(u.x << 16);
    r.y = __uint_as_float(u.x & 0xffff0000u);
    r.z = __uint_as_float(u.y << 16);
    r.w = __uint_as_float(u.y & 0xffff0000u);
    return r;
}
__device__ __forceinline__ unsigned pack_sn(int s, float n) {
    return (unsigned)s | ((unsigned)__half_as_ushort(__float2half_rn(n)) << 16);
}
__device__ __forceinline__ float unpack_n(unsigned p) {
    return __half2float(__ushort_as_half((unsigned short)(p >> 16)));
}

// ---------------- init: seed bucket cursors (1 block) ----------------
__global__ void init_k(int* __restrict__ gcur) {
    if (threadIdx.x < NBUCK) gcur[threadIdx.x] = threadIdx.x * MAXB;
}

// ---------------- fused: bin_scatter (blocks 0..390) || gemm1 (blocks 391..1953) ----------
union FusedSh {
    struct { float WT[64 * 68]; } g;                             // 17408 B
    struct {
        int hist[NBUCK]; int lofs[NBUCK]; int gbase[NBUCK]; int cur[NBUCK];
        int sc[256]; unsigned stage[CHUNK];
    } s;                                                         // 12352 B
};
__global__ __launch_bounds__(256) void gemm1_scatter(
        const float* __restrict__ x, const float* __restrict__ W1,
        unsigned short* __restrict__ xwout,
        const int* __restrict__ ei, int* __restrict__ gcur, unsigned* __restrict__ ebuf) {
    __shared__ FusedSh sh;
    int tid = threadIdx.x;
    if (blockIdx.x < SCAT_BLK) {
        // ---- scatter path ----
        for (int i = tid; i < NBUCK; i += 256) sh.s.hist[i] = 0;
        __syncthreads();
        int e0 = blockIdx.x * CHUNK;
        int n = min(CHUNK, N_EDGES - e0);
        int src[8], dst[8];
#pragma unroll
        for (int k = 0; k < 8; ++k) {
            int idx = k * 256 + tid;
            if (idx < n) {
                int e = e0 + idx;
                src[k] = ei[e];
                dst[k] = ei[N_EDGES + e];
                atomicAdd(&sh.s.hist[dst[k] >> 8], 1);
            } else dst[k] = -1;
        }
        __syncthreads();
        int v = (tid < NBUCK) ? sh.s.hist[tid] : 0;
        sh.s.sc[tid] = v;
        __syncthreads();
        for (int off = 1; off < 256; off <<= 1) {
            int t = (tid >= off) ? sh.s.sc[tid - off] : 0;
            __syncthreads();
            sh.s.sc[tid] += t;
            __syncthreads();
        }
        if (tid < NBUCK) {
            int ex = sh.s.sc[tid] - v;
            sh.s.lofs[tid] = ex;
            sh.s.cur[tid] = ex;
            sh.s.gbase[tid] = v ? atomicAdd(&gcur[tid], v) : 0;
        }
        __syncthreads();
#pragma unroll
        for (int k = 0; k < 8; ++k) {
            if (dst[k] >= 0) {
                int b = dst[k] >> 8;
                int p = atomicAdd(&sh.s.cur[b], 1);
                sh.s.stage[p] = (unsigned)src[k] | ((unsigned)(dst[k] & 255) << 16)
                                                | ((unsigned)b << 24);
            }
        }
        __syncthreads();
        for (int i = tid; i < n; i += 256) {
            unsigned p = sh.s.stage[i];
            int b = p >> 24;
            ebuf[sh.s.gbase[b] + (i - sh.s.lofs[b])] = p;   // contiguous per bucket
        }
    } else {
        // ---- gemm path (f32 input) ----
        for (int i = tid; i < 64 * 64; i += 256) {
            int k = i >> 6, c = i & 63;
            sh.g.WT[c * 68 + k] = W1[i];
        }
        __syncthreads();
        int lane = tid & 63;
        int wv = __builtin_amdgcn_readfirstlane(tid >> 6);
        int row0 = (blockIdx.x - SCAT_BLK) * 32 + wv * 8;
        if (row0 >= N_NODES) return;
        float acc[8] = {0.f, 0.f, 0.f, 0.f, 0.f, 0.f, 0.f, 0.f};
#pragma unroll 2
        for (int k = 0; k < 64; k += 4) {
            float4 w = *(const float4*)&sh.g.WT[lane * 68 + k];
#pragma unroll
            for (int r = 0; r < 8; ++r) {
                float4 xv = *(const float4*)&x[(size_t)(row0 + r) * 64 + k];  // scalar load
                acc[r] = fmaf(xv.x, w.x, acc[r]);
                acc[r] = fmaf(xv.y, w.y, acc[r]);
                acc[r] = fmaf(xv.z, w.z, acc[r]);
                acc[r] = fmaf(xv.w, w.w, acc[r]);
            }
        }
#pragma unroll
        for (int r = 0; r < 8; ++r)
            xwout[(size_t)(row0 + r) * 64 + lane] = (unsigned short)bf16_rne(acc[r]);
    }
}

// -------- per-bucket CSR build (deg, rowp, dinv, col) + POOL/CNT zero ----------
__global__ void csr_bucket(const unsigned* __restrict__ ebuf, const int* __restrict__ gcur,
                           int* __restrict__ deg, int* __restrict__ rowp,
                           float* __restrict__ dinv, int* __restrict__ col,
                           float* __restrict__ poolz) {
    __shared__ int nd[256];
    __shared__ int cur[256];
    __shared__ int sc[256];
    int b = blockIdx.x;
    int tid = threadIdx.x;
    {
        int zi = b * 85 + (tid % 85);
        if (tid < 85 && zi < N_GRAPHS * CH + N_GRAPHS) poolz[zi] = 0.0f;
    }
    nd[tid] = 0;
    __syncthreads();
    int es = b * MAXB, ee = gcur[b];
    for (int e = es + tid; e < ee; e += 256)
        atomicAdd(&nd[(ebuf[e] >> 16) & 255], 1);
    __syncthreads();
    int v = nd[tid];
    sc[tid] = v;
    __syncthreads();
    for (int off = 1; off < 256; off <<= 1) {
        int t = (tid >= off) ? sc[tid - off] : 0;
        __syncthreads();
        sc[tid] += t;
        __syncthreads();
    }
    int node = b * 256 + tid;
    int lstart = es + sc[tid] - v;
    if (node < N_NODES) {
        deg[node] = v;
        rowp[node] = lstart;
        dinv[node] = rsqrtf((float)v + 1.0f);
    }
    cur[tid] = lstart;
    __syncthreads();
    for (int e = es + tid; e < ee; e += 256) {
        unsigned p = ebuf[e];
        int pos = atomicAdd(&cur[(p >> 16) & 255], 1);
        col[pos] = (int)(p & 0xFFFFu);
    }
}

// ---- fused layer-1 agg + gemm2: 2 nodes/wave, W2 slice register-cached across both ----
__device__ __forceinline__ void agg1_core(
        int node, int lane, int q, int c4,
        const int* __restrict__ rowp, const int* __restrict__ deg,
        const int* __restrict__ col, const float* __restrict__ dinv,
        unsigned* __restrict__ pck, const unsigned short* __restrict__ tab,
        const float* __restrict__ b1, unsigned& h0out, unsigned& h1out) {
    float dd = dinv[node];
    int cnt = deg[node];
    int start = rowp[node];
    float4 acc = make_float4(0.f, 0.f, 0.f, 0.f);
    if (q == 0) {
        float4 xs = ldtab(tab, node, c4);
        float dd2 = dd * dd;
        acc.x = xs.x * dd2; acc.y = xs.y * dd2; acc.z = xs.z * dd2; acc.w = xs.w * dd2;
    }
    int j = 0;
    for (; j + 16 <= cnt; j += 16) {
        int s[4]; float nv[4];
#pragma unroll
        for (int u = 0; u < 4; ++u) {
            int idx = start + j + 4 * u + q;
            s[u] = col[idx];
            nv[u] = dinv[s[u]] * dd;
            if ((lane & 15) == 0) pck[idx] = pack_sn(s[u], nv[u]);
        }
#pragma unroll
        for (int u = 0; u < 4; ++u) {
            float4 xv = ldtab(tab, s[u], c4);
            acc.x = fmaf(nv[u], xv.x, acc.x); acc.y = fmaf(nv[u], xv.y, acc.y);
            acc.z = fmaf(nv[u], xv.z, acc.z); acc.w = fmaf(nv[u], xv.w, acc.w);
        }
    }
    for (; j + 8 <= cnt; j += 8) {
        int s[2]; float nv[2];
#pragma unroll
        for (int u = 0; u < 2; ++u) {
            int idx = start + j + 4 * u + q;
            s[u] = col[idx];
            nv[u] = dinv[s[u]] * dd;
            if ((lane & 15) == 0) pck[idx] = pack_sn(s[u], nv[u]);
        }
#pragma unroll
        for (int u = 0; u < 2; ++u) {
            float4 xv = ldtab(tab, s[u], c4);
            acc.x = fmaf(nv[u], xv.x, acc.x); acc.y = fmaf(nv[u], xv.y, acc.y);
            acc.z = fmaf(nv[u], xv.z, acc.z); acc.w = fmaf(nv[u], xv.w, acc.w);
        }
    }
    for (; j < cnt; j += 4) {
        int jj = j + q;
        bool valid = jj < cnt;
        int s = col[start + (valid ? jj : 0)];
        float nv = valid ? dinv[s] * dd : 0.0f;
        if (valid && (lane & 15) == 0) pck[start + jj] = pack_sn(s, nv);
        float4 xv = ldtab(tab, s, c4);
        acc.x = fmaf(nv, xv.x, acc.x); acc.y = fmaf(nv, xv.y, acc.y);
        acc.z = fmaf(nv, xv.z, acc.z); acc.w = fmaf(nv, xv.w, acc.w);
    }
    acc.x += __shfl_xor(acc.x, 16); acc.y += __shfl_xor(acc.y, 16);
    acc.z += __shfl_xor(acc.z, 16); acc.w += __shfl_xor(acc.w, 16);
    acc.x += __shfl_xor(acc.x, 32); acc.y += __shfl_xor(acc.y, 32);
    acc.z += __shfl_xor(acc.z, 32); acc.w += __shfl_xor(acc.w, 32);
    float4 bv = *(const float4*)&b1[c4];
    acc.x = fmaxf(acc.x + bv.x, 0.f); acc.y = fmaxf(acc.y + bv.y, 0.f);
    acc.z = fmaxf(acc.z + bv.z, 0.f); acc.w = fmaxf(acc.w + bv.w, 0.f);
    h0out = bf16_rne(acc.x) | (bf16_rne(acc.y) << 16);
    h1out = bf16_rne(acc.z) | (bf16_rne(acc.w) << 16);
}

__device__ __forceinline__ void gemm2_epi(
        int node, int q, int c4, unsigned h0, unsigned h1,
        const float4* __restrict__ w,            // 16 cached W2 float4s
        unsigned short* __restrict__ xw2out) {
    float hq[16];
#pragma unroll
    for (int t = 0; t < 4; ++t) {
        int sl = 4 * q + t;
        unsigned v0 = (unsigned)__shfl((int)h0, sl, 64);
        unsigned v1 = (unsigned)__shfl((int)h1, sl, 64);
        hq[4 * t + 0] = __uint_as_float(v0 << 16);
        hq[4 * t + 1] = __uint_as_float(v0 & 0xffff0000u);
        hq[4 * t + 2] = __uint_as_float(v1 << 16);
        hq[4 * t + 3] = __uint_as_float(v1 & 0xffff0000u);
    }
    float4 g = make_float4(0.f, 0.f, 0.f, 0.f);
#pragma unroll
    for (int kk = 0; kk < 16; ++kk) {
        g.x = fmaf(hq[kk], w[kk].x, g.x); g.y = fmaf(hq[kk], w[kk].y, g.y);
        g.z = fmaf(hq[kk], w[kk].z, g.z); g.w = fmaf(hq[kk], w[kk].w, g.w);
    }
    g.x += __shfl_xor(g.x, 16); g.y += __shfl_xor(g.y, 16);
    g.z += __shfl_xor(g.z, 16); g.w += __shfl_xor(g.w, 16);
    g.x += __shfl_xor(g.x, 32); g.y += __shfl_xor(g.y, 32);
    g.z += __shfl_xor(g.z, 32); g.w += __shfl_xor(g.w, 32);
    if (q == 0) {
        uint2 o;
        o.x = bf16_rne(g.x) | (bf16_rne(g.y) << 16);
        o.y = bf16_rne(g.z) | (bf16_rne(g.w) << 16);
        *(uint2*)&xw2out[((size_t)node << 6) + c4] = o;
    }
}

__global__ void agg1_gemm2(const int* __restrict__ rowp, const int* __restrict__ deg,
                           const int* __restrict__ col, const float* __restrict__ dinv,
                           unsigned* __restrict__ pck,
                           const unsigned short* __restrict__ tab,
                           const float* __restrict__ b1, const float* __restrict__ W2,
                           unsigned short* __restrict__ xw2out) {
    int tid = threadIdx.x;
    int wv = __builtin_amdgcn_readfirstlane(tid >> 6);
    int lane = tid & 63;
    int q = lane >> 4;
    int c4 = (lane & 15) << 2;
    int node0 = blockIdx.x * 8 + wv * 2;             // grid*8 == N_NODES exactly
    unsigned a0, a1, b0h, b1h;
    agg1_core(node0,     lane, q, c4, rowp, deg, col, dinv, pck, tab, b1, a0, a1);
    agg1_core(node0 + 1, lane, q, c4, rowp, deg, col, dinv, pck, tab, b1, b0h, b1h);
    // load W2 slice once (16 float4 -> 64 VGPRs), reuse for both epilogues
    float4 w[16];
#pragma unroll
    for (int kk = 0; kk < 16; ++kk)
        w[kk] = *(const float4*)&W2[((16 * q + kk) << 6) + c4];
    gemm2_epi(node0,     q, c4, a0, a1, w, xw2out);
    gemm2_epi(node0 + 1, q, c4, b0h, b1h, w, xw2out);
}

// ---------------- plain aggregation (layers 2-3), packed-edge stream ----------------
__global__ void agg_v4(const int* __restrict__ rowp, const int* __restrict__ deg,
                       const float* __restrict__ dinv, const unsigned* __restrict__ pck,
                       const unsigned short* __restrict__ tab, const float* __restrict__ bias,
                       unsigned short* __restrict__ outv, int do_relu) {
    int wv = __builtin_amdgcn_readfirstlane(threadIdx.x >> 6);
    int node = blockIdx.x * 4 + wv;
    int lane = threadIdx.x & 63;
    int q = lane >> 4;
    int c4 = (lane & 15) << 2;
    float dd = dinv[node];
    int cnt = deg[node];
    int start = rowp[node];
    float4 acc = make_float4(0.f, 0.f, 0.f, 0.f);
    if (q == 0) {
        float4 xs = ldtab(tab, node, c4);
        float dd2 = dd * dd;
        acc.x = xs.x * dd2; acc.y = xs.y * dd2; acc.z = xs.z * dd2; acc.w = xs.w * dd2;
    }
    int j = 0;
    for (; j + 16 <= cnt; j += 16) {
        int s[4]; float nv[4];
#pragma unroll
        for (int u = 0; u < 4; ++u) {
            unsigned p = pck[start + j + 4 * u + q];
            s[u] = (int)(p & 0xFFFFu);
            nv[u] = unpack_n(p);
        }
#pragma unroll
        for (int u = 0; u < 4; ++u) {
            float4 xv = ldtab(tab, s[u], c4);
            acc.x = fmaf(nv[u], xv.x, acc.x); acc.y = fmaf(nv[u], xv.y, acc.y);
            acc.z = fmaf(nv[u], xv.z, acc.z); acc.w = fmaf(nv[u], xv.w, acc.w);
        }
    }
    for (; j + 8 <= cnt; j += 8) {
        int s[2]; float nv[2];
#pragma unroll
        for (int u = 0; u < 2; ++u) {
            unsigned p = pck[start + j + 4 * u + q];
            s[u] = (int)(p & 0xFFFFu);
            nv[u] = unpack_n(p);
        }
#pragma unroll
        for (int u = 0; u < 2; ++u) {
            float4 xv = ldtab(tab, s[u], c4);
            acc.x = fmaf(nv[u], xv.x, acc.x); acc.y = fmaf(nv[u], xv.y, acc.y);
            acc.z = fmaf(nv[u], xv.z, acc.z); acc.w = fmaf(nv[u], xv.w, acc.w);
        }
    }
    for (; j < cnt; j += 4) {
        int jj = j + q;
        bool valid = jj < cnt;
        unsigned p = pck[start + (valid ? jj : 0)];
        int s = (int)(p & 0xFFFFu);
        float nv = valid ? unpack_n(p) : 0.0f;
        float4 xv = ldtab(tab, s, c4);
        acc.x = fmaf(nv, xv.x, acc.x); acc.y = fmaf(nv, xv.y, acc.y);
        acc.z = fmaf(nv, xv.z, acc.z); acc.w = fmaf(nv, xv.w, acc.w);
    }
    acc.x += __shfl_xor(acc.x, 16); acc.y += __shfl_xor(acc.y, 16);
    acc.z += __shfl_xor(acc.z, 16); acc.w += __shfl_xor(acc.w, 16);
    acc.x += __shfl_xor(acc.x, 32); acc.y += __shfl_xor(acc.y, 32);
    acc.z += __shfl_xor(acc.z, 32); acc.w += __shfl_xor(acc.w, 32);
    if (q == 0) {
        if (bias) {
            float4 bv = *(const float4*)&bias[c4];
            acc.x += bv.x; acc.y += bv.y; acc.z += bv.z; acc.w += bv.w;
        }
        if (do_relu) {
            acc.x = fmaxf(acc.x, 0.f); acc.y = fmaxf(acc.y, 0.f);
            acc.z = fmaxf(acc.z, 0.f); acc.w = fmaxf(acc.w, 0.f);
        }
        uint2 o;
        o.x = bf16_rne(acc.x) | (bf16_rne(acc.y) << 16);
        o.y = bf16_rne(acc.z) | (bf16_rne(acc.w) << 16);
        *(uint2*)&outv[((size_t)node << 6) + c4] = o;
    }
}

// ---------------- pool over bf16 Z (+ per-graph node count): batch sorted ----------------
__global__ void pool_seg(const unsigned short* __restrict__ h, const int* __restrict__ batch,
                         float* __restrict__ pool, float* __restrict__ cntg) {
    int ch = threadIdx.x & 63;
    int grp = threadIdx.x >> 6;
    int base = (blockIdx.x * 4 + grp) * 16;
    float acc = 0.0f;
    int curg = -1, runlen = 0;
    for (int n = 0; n < 16; ++n) {
        int node = base + n;
        if (node >= N_NODES) break;
        int g = batch[node];
        float v = __uint_as_float(((unsigned)h[((size_t)node << 6) + ch]) << 16);
        if (g != curg) {
            if (curg >= 0) {
                atomicAdd(&pool[curg * 64 + ch], acc);
                if (ch == 0) atomicAdd(&cntg[curg], (float)runlen);
            }
            curg = g; acc = v; runlen = 1;
        } else { acc += v; runlen++; }
    }
    if (curg >= 0) {
        atomicAdd(&pool[curg * 64 + ch], acc);
        if (ch == 0) atomicAdd(&cntg[curg], (float)runlen);
    }
}

// ---------------- tiny output GEMM: out = P @ W3 + cnt_g * b3 ----------------
__global__ void out_gemm(const float* __restrict__ P, const float* __restrict__ cntg,
                         const float* __restrict__ W, const float* __restrict__ b,
                         float* __restrict__ out) {
    __shared__ float Ws[64 * 64];
    int tid = threadIdx.x;
    for (int i = tid; i < 64 * 64; i += 256) Ws[i] = W[i];
    __syncthreads();
    int lane = tid & 63;
    int g = blockIdx.x * 4 + (tid >> 6);
    if (g >= N_GRAPHS) return;
    float pv = P[g * 64 + lane];
    float acc = 0.0f;
#pragma unroll
    for (int k = 0; k < 64; ++k)
        acc = fmaf(__shfl(pv, k, 64), Ws[k * 64 + lane], acc);
    out[g * 64 + lane] = acc + cntg[g] * b[lane];
}

extern "C" void kernel_launch(void* const* d_in, const int* in_sizes, int n_in,
                              void* d_out, int out_size, void* d_ws, size_t ws_size,
                              hipStream_t stream) {
    const float* x   = (const float*)d_in[0];
    const int* ei    = (const int*)d_in[1];   // int32 [2, N_EDGES]
    const int* batch = (const int*)d_in[2];   // int32 [N_NODES]
    const float* W1  = (const float*)d_in[3];
    const float* b1  = (const float*)d_in[4];
    const float* W2  = (const float*)d_in[5];
    const float* b2  = (const float*)d_in[6];
    const float* W3  = (const float*)d_in[7];
    const float* b3  = (const float*)d_in[8];
    float* out = (float*)d_out;

    // workspace layout (bytes), total ~37.1MB; PCK/COL/EBUF sized for NPAD=903168
    char* ws = (char*)d_ws;
    float*    dinv = (float*)(ws);                   // 50048 f32   -> ends   200192
    int*      DEG  = (int*)(ws + 200192);            // 50048 i32   -> ends   400384
    int*      ROWP = (int*)(ws + 400384);            // 50048 i32   -> ends   600576
    int*      COL  = (int*)(ws + 600576);            // NPAD i32    -> ends  4213248
    unsigned* PCK  = (unsigned*)(ws + 4213248);      // NPAD u32    -> ends  7825920
    float*    XW   = (float*)(ws + 7825920);         // 12.8MB      -> ends 20625920
    float*    ACC  = (float*)(ws + 20625920);        // 12.8MB      -> ends 33425920
    float*    POOL = (float*)(ws + 33425920);        // 16384 f32   -> ends 33491456
    float*    CNT  = (float*)(ws + 33491456);        // 256 f32 (contiguous after POOL)
    int*      GCUR = (int*)(ws + 33492480);          // 196 i32
    unsigned* EBUF = (unsigned*)(ws + 33493504);     // NPAD u32    -> ends 37106176

    const int WAVE_NODE_BLK = N_NODES / 4;           // 12500 (exact)

    // ---- init bucket cursors
    init_k<<<1, 256, 0, stream>>>(GCUR);

    // ---- fused: edge bin-scatter (391 blks) || gemm1 x@W1->XW1 bf16 (1563 blks)
    gemm1_scatter<<<SCAT_BLK + GEMM_BLK, 256, 0, stream>>>(
        x, W1, (unsigned short*)XW, ei, GCUR, EBUF);

    // ---- per-bucket CSR finalize (+ POOL/CNT zero)
    csr_bucket<<<NBUCK, 256, 0, stream>>>(EBUF, GCUR, DEG, ROWP, dinv, COL, POOL);

    // ---- fused layer-1 agg + gemm2: 2 nodes/wave, W2 register-cached
    agg1_gemm2<<<N_NODES / 8, 256, 0, stream>>>(ROWP, DEG, COL, dinv, PCK,
        (const unsigned short*)XW, b1, W2, (unsigned short*)ACC);

    // ---- layer 2 agg: XW2 -> H2(bf16) in XW
    agg_v4<<<WAVE_NODE_BLK, 256, 0, stream>>>(ROWP, DEG, dinv, PCK,
        (const unsigned short*)ACC, b2, (unsigned short*)XW, 1);

    // ---- layer 3 (reordered): Z = A_hat H2 -> bf16 in ACC -> pool -> small GEMM
    agg_v4<<<WAVE_NODE_BLK, 256, 0, stream>>>(ROWP, DEG, dinv, PCK,
        (const unsigned short*)XW, nullptr, (unsigned short*)ACC, 0);
    pool_seg<<<(N_NODES + 63) / 64, 256, 0, stream>>>((const unsigned short*)ACC,
        batch, POOL, CNT);
    out_gemm<<<N_GRAPHS / 4, 256, 0, stream>>>(POOL, CNT, W3, b3, out);
}

// Round 18
// 222.904 us; speedup vs baseline: 1.0343x; 1.0343x over previous
//
#include <hip/hip_runtime.h>
#include <hip/hip_bf16.h>
#include <hip/hip_fp16.h>

#define N_NODES 50000
#define N_EDGES 800000
#define CH 64
#define N_GRAPHS 256
#define NBUCK 196            // ceil(50000/256); bucket = dst >> 8
#define MAXB 4608            // padded bucket capacity (mean 4096, sigma~64)
#define NPAD (NBUCK * MAXB)  // 903168 padded edge slots
#define CHUNK 2048           // edges staged per scatter block
#define SCAT_BLK ((N_EDGES + CHUNK - 1) / CHUNK)   // 391
#define GEMM_BLK ((N_NODES + 31) / 32)             // 1563

__device__ __forceinline__ unsigned bf16_rne(float f) {
    unsigned u = __float_as_uint(f);
    return (u + 0x7fffu + ((u >> 16) & 1u)) >> 16;
}
__device__ __forceinline__ float4 ldtab(const unsigned short* __restrict__ tab, int s, int c4) {
    uint2 u = *(const uint2*)(tab + ((size_t)s << 6) + c4);
    float4 r;
    r.x = __uint_as_float(u.x << 16);
    r.y = __uint_as_float(u.x & 0xffff0000u);
    r.z = __uint_as_float(u.y << 16);
    r.w = __uint_as_float(u.y & 0xffff0000u);
    return r;
}
__device__ __forceinline__ unsigned pack_sn(int s, float n) {
    return (unsigned)s | ((unsigned)__half_as_ushort(__float2half_rn(n)) << 16);
}
__device__ __forceinline__ float unpack_n(unsigned p) {
    return __half2float(__ushort_as_half((unsigned short)(p >> 16)));
}

// ---------------- init: seed bucket cursors (1 block) ----------------
__global__ void init_k(int* __restrict__ gcur) {
    if (threadIdx.x < NBUCK) gcur[threadIdx.x] = threadIdx.x * MAXB;
}

// ---------------- fused: bin_scatter (blocks 0..390) || gemm1 (blocks 391..1953) ----------
union FusedSh {
    struct { float WT[64 * 68]; } g;                             // 17408 B
    struct {
        int hist[NBUCK]; int lofs[NBUCK]; int gbase[NBUCK]; int cur[NBUCK];
        int sc[256]; unsigned stage[CHUNK];
    } s;                                                         // 12352 B
};
__global__ __launch_bounds__(256) void gemm1_scatter(
        const float* __restrict__ x, const float* __restrict__ W1,
        unsigned short* __restrict__ xwout,
        const int* __restrict__ ei, int* __restrict__ gcur, unsigned* __restrict__ ebuf) {
    __shared__ FusedSh sh;
    int tid = threadIdx.x;
    if (blockIdx.x < SCAT_BLK) {
        // ---- scatter path ----
        for (int i = tid; i < NBUCK; i += 256) sh.s.hist[i] = 0;
        __syncthreads();
        int e0 = blockIdx.x * CHUNK;
        int n = min(CHUNK, N_EDGES - e0);
        int src[8], dst[8];
#pragma unroll
        for (int k = 0; k < 8; ++k) {
            int idx = k * 256 + tid;
            if (idx < n) {
                int e = e0 + idx;
                src[k] = ei[e];
                dst[k] = ei[N_EDGES + e];
                atomicAdd(&sh.s.hist[dst[k] >> 8], 1);
            } else dst[k] = -1;
        }
        __syncthreads();
        int v = (tid < NBUCK) ? sh.s.hist[tid] : 0;
        sh.s.sc[tid] = v;
        __syncthreads();
        for (int off = 1; off < 256; off <<= 1) {
            int t = (tid >= off) ? sh.s.sc[tid - off] : 0;
            __syncthreads();
            sh.s.sc[tid] += t;
            __syncthreads();
        }
        if (tid < NBUCK) {
            int ex = sh.s.sc[tid] - v;
            sh.s.lofs[tid] = ex;
            sh.s.cur[tid] = ex;
            sh.s.gbase[tid] = v ? atomicAdd(&gcur[tid], v) : 0;
        }
        __syncthreads();
#pragma unroll
        for (int k = 0; k < 8; ++k) {
            if (dst[k] >= 0) {
                int b = dst[k] >> 8;
                int p = atomicAdd(&sh.s.cur[b], 1);
                sh.s.stage[p] = (unsigned)src[k] | ((unsigned)(dst[k] & 255) << 16)
                                                | ((unsigned)b << 24);
            }
        }
        __syncthreads();
        for (int i = tid; i < n; i += 256) {
            unsigned p = sh.s.stage[i];
            int b = p >> 24;
            ebuf[sh.s.gbase[b] + (i - sh.s.lofs[b])] = p;   // contiguous per bucket
        }
    } else {
        // ---- gemm path (f32 input) ----
        for (int i = tid; i < 64 * 64; i += 256) {
            int k = i >> 6, c = i & 63;
            sh.g.WT[c * 68 + k] = W1[i];
        }
        __syncthreads();
        int lane = tid & 63;
        int wv = __builtin_amdgcn_readfirstlane(tid >> 6);
        int row0 = (blockIdx.x - SCAT_BLK) * 32 + wv * 8;
        if (row0 >= N_NODES) return;
        float acc[8] = {0.f, 0.f, 0.f, 0.f, 0.f, 0.f, 0.f, 0.f};
#pragma unroll 2
        for (int k = 0; k < 64; k += 4) {
            float4 w = *(const float4*)&sh.g.WT[lane * 68 + k];
#pragma unroll
            for (int r = 0; r < 8; ++r) {
                float4 xv = *(const float4*)&x[(size_t)(row0 + r) * 64 + k];  // scalar load
                acc[r] = fmaf(xv.x, w.x, acc[r]);
                acc[r] = fmaf(xv.y, w.y, acc[r]);
                acc[r] = fmaf(xv.z, w.z, acc[r]);
                acc[r] = fmaf(xv.w, w.w, acc[r]);
            }
        }
#pragma unroll
        for (int r = 0; r < 8; ++r)
            xwout[(size_t)(row0 + r) * 64 + lane] = (unsigned short)bf16_rne(acc[r]);
    }
}

// -------- per-bucket CSR build (deg, rowp, dinv, col) + POOL/CNT zero ----------
__global__ void csr_bucket(const unsigned* __restrict__ ebuf, const int* __restrict__ gcur,
                           int* __restrict__ deg, int* __restrict__ rowp,
                           float* __restrict__ dinv, int* __restrict__ col,
                           float* __restrict__ poolz) {
    __shared__ int nd[256];
    __shared__ int cur[256];
    __shared__ int sc[256];
    int b = blockIdx.x;
    int tid = threadIdx.x;
    {
        int zi = b * 85 + (tid % 85);
        if (tid < 85 && zi < N_GRAPHS * CH + N_GRAPHS) poolz[zi] = 0.0f;
    }
    nd[tid] = 0;
    __syncthreads();
    int es = b * MAXB, ee = gcur[b];
    for (int e = es + tid; e < ee; e += 256)
        atomicAdd(&nd[(ebuf[e] >> 16) & 255], 1);
    __syncthreads();
    int v = nd[tid];
    sc[tid] = v;
    __syncthreads();
    for (int off = 1; off < 256; off <<= 1) {
        int t = (tid >= off) ? sc[tid - off] : 0;
        __syncthreads();
        sc[tid] += t;
        __syncthreads();
    }
    int node = b * 256 + tid;
    int lstart = es + sc[tid] - v;
    if (node < N_NODES) {
        deg[node] = v;
        rowp[node] = lstart;
        dinv[node] = rsqrtf((float)v + 1.0f);
    }
    cur[tid] = lstart;
    __syncthreads();
    for (int e = es + tid; e < ee; e += 256) {
        unsigned p = ebuf[e];
        int pos = atomicAdd(&cur[(p >> 16) & 255], 1);
        col[pos] = (int)(p & 0xFFFFu);
    }
}

// ---- fused layer-1 agg + gemm2, LDS-free epilogue (R15 winner: 1 node/wave, VGPR=32) ----
__global__ void agg1_gemm2(const int* __restrict__ rowp, const int* __restrict__ deg,
                           const int* __restrict__ col, const float* __restrict__ dinv,
                           unsigned* __restrict__ pck,
                           const unsigned short* __restrict__ tab,
                           const float* __restrict__ b1, const float* __restrict__ W2,
                           unsigned short* __restrict__ xw2out) {
    int tid = threadIdx.x;
    int wv = __builtin_amdgcn_readfirstlane(tid >> 6);
    int node = blockIdx.x * 4 + wv;
    int lane = tid & 63;
    int q = lane >> 4;
    int c4 = (lane & 15) << 2;
    float dd = dinv[node];
    int cnt = deg[node];
    int start = rowp[node];
    float4 acc = make_float4(0.f, 0.f, 0.f, 0.f);
    if (q == 0) {
        float4 xs = ldtab(tab, node, c4);
        float dd2 = dd * dd;
        acc.x = xs.x * dd2; acc.y = xs.y * dd2; acc.z = xs.z * dd2; acc.w = xs.w * dd2;
    }
    int j = 0;
    for (; j + 16 <= cnt; j += 16) {
        int s[4]; float nv[4];
#pragma unroll
        for (int u = 0; u < 4; ++u) {
            int idx = start + j + 4 * u + q;
            s[u] = col[idx];
            nv[u] = dinv[s[u]] * dd;
            if ((lane & 15) == 0) pck[idx] = pack_sn(s[u], nv[u]);
        }
#pragma unroll
        for (int u = 0; u < 4; ++u) {
            float4 xv = ldtab(tab, s[u], c4);
            acc.x = fmaf(nv[u], xv.x, acc.x); acc.y = fmaf(nv[u], xv.y, acc.y);
            acc.z = fmaf(nv[u], xv.z, acc.z); acc.w = fmaf(nv[u], xv.w, acc.w);
        }
    }
    for (; j + 8 <= cnt; j += 8) {
        int s[2]; float nv[2];
#pragma unroll
        for (int u = 0; u < 2; ++u) {
            int idx = start + j + 4 * u + q;
            s[u] = col[idx];
            nv[u] = dinv[s[u]] * dd;
            if ((lane & 15) == 0) pck[idx] = pack_sn(s[u], nv[u]);
        }
#pragma unroll
        for (int u = 0; u < 2; ++u) {
            float4 xv = ldtab(tab, s[u], c4);
            acc.x = fmaf(nv[u], xv.x, acc.x); acc.y = fmaf(nv[u], xv.y, acc.y);
            acc.z = fmaf(nv[u], xv.z, acc.z); acc.w = fmaf(nv[u], xv.w, acc.w);
        }
    }
    for (; j < cnt; j += 4) {
        int jj = j + q;
        bool valid = jj < cnt;
        int s = col[start + (valid ? jj : 0)];
        float nv = valid ? dinv[s] * dd : 0.0f;
        if (valid && (lane & 15) == 0) pck[start + jj] = pack_sn(s, nv);
        float4 xv = ldtab(tab, s, c4);
        acc.x = fmaf(nv, xv.x, acc.x); acc.y = fmaf(nv, xv.y, acc.y);
        acc.z = fmaf(nv, xv.z, acc.z); acc.w = fmaf(nv, xv.w, acc.w);
    }
    acc.x += __shfl_xor(acc.x, 16); acc.y += __shfl_xor(acc.y, 16);
    acc.z += __shfl_xor(acc.z, 16); acc.w += __shfl_xor(acc.w, 16);
    acc.x += __shfl_xor(acc.x, 32); acc.y += __shfl_xor(acc.y, 32);
    acc.z += __shfl_xor(acc.z, 32); acc.w += __shfl_xor(acc.w, 32);
    // all lanes now hold the full H1 quad (c4..c4+3) = relu(acc + b1)
    {
        float4 bv = *(const float4*)&b1[c4];
        acc.x = fmaxf(acc.x + bv.x, 0.f); acc.y = fmaxf(acc.y + bv.y, 0.f);
        acc.z = fmaxf(acc.z + bv.z, 0.f); acc.w = fmaxf(acc.w + bv.w, 0.f);
    }
    // pack H1 quad to bf16; 8 bpermutes instead of 16
    unsigned h0 = bf16_rne(acc.x) | (bf16_rne(acc.y) << 16);
    unsigned h1 = bf16_rne(acc.z) | (bf16_rne(acc.w) << 16);
    // epilogue GEMM: lane accumulates out[c4..c4+3] over k in [16q, 16q+16)
    float hq[16];
#pragma unroll
    for (int t = 0; t < 4; ++t) {
        int sl = 4 * q + t;                      // lane holding H1 quad for k=4*sl..+3
        unsigned v0 = (unsigned)__shfl((int)h0, sl, 64);
        unsigned v1 = (unsigned)__shfl((int)h1, sl, 64);
        hq[4 * t + 0] = __uint_as_float(v0 << 16);
        hq[4 * t + 1] = __uint_as_float(v0 & 0xffff0000u);
        hq[4 * t + 2] = __uint_as_float(v1 << 16);
        hq[4 * t + 3] = __uint_as_float(v1 & 0xffff0000u);
    }
    float4 g = make_float4(0.f, 0.f, 0.f, 0.f);
#pragma unroll
    for (int kk = 0; kk < 16; ++kk) {
        int k = 16 * q + kk;
        float4 wv = *(const float4*)&W2[(k << 6) + c4];   // global, L1-resident (16KB)
        g.x = fmaf(hq[kk], wv.x, g.x); g.y = fmaf(hq[kk], wv.y, g.y);
        g.z = fmaf(hq[kk], wv.z, g.z); g.w = fmaf(hq[kk], wv.w, g.w);
    }
    g.x += __shfl_xor(g.x, 16); g.y += __shfl_xor(g.y, 16);
    g.z += __shfl_xor(g.z, 16); g.w += __shfl_xor(g.w, 16);
    g.x += __shfl_xor(g.x, 32); g.y += __shfl_xor(g.y, 32);
    g.z += __shfl_xor(g.z, 32); g.w += __shfl_xor(g.w, 32);
    if (q == 0) {
        uint2 o;
        o.x = bf16_rne(g.x) | (bf16_rne(g.y) << 16);
        o.y = bf16_rne(g.z) | (bf16_rne(g.w) << 16);
        *(uint2*)&xw2out[((size_t)node << 6) + c4] = o;
    }
}

// ---------------- plain aggregation (layers 2-3), packed-edge stream ----------------
__global__ void agg_v4(const int* __restrict__ rowp, const int* __restrict__ deg,
                       const float* __restrict__ dinv, const unsigned* __restrict__ pck,
                       const unsigned short* __restrict__ tab, const float* __restrict__ bias,
                       unsigned short* __restrict__ outv, int do_relu) {
    int wv = __builtin_amdgcn_readfirstlane(threadIdx.x >> 6);
    int node = blockIdx.x * 4 + wv;
    int lane = threadIdx.x & 63;
    int q = lane >> 4;
    int c4 = (lane & 15) << 2;
    float dd = dinv[node];
    int cnt = deg[node];
    int start = rowp[node];
    float4 acc = make_float4(0.f, 0.f, 0.f, 0.f);
    if (q == 0) {
        float4 xs = ldtab(tab, node, c4);
        float dd2 = dd * dd;
        acc.x = xs.x * dd2; acc.y = xs.y * dd2; acc.z = xs.z * dd2; acc.w = xs.w * dd2;
    }
    int j = 0;
    for (; j + 16 <= cnt; j += 16) {
        int s[4]; float nv[4];
#pragma unroll
        for (int u = 0; u < 4; ++u) {
            unsigned p = pck[start + j + 4 * u + q];
            s[u] = (int)(p & 0xFFFFu);
            nv[u] = unpack_n(p);
        }
#pragma unroll
        for (int u = 0; u < 4; ++u) {
            float4 xv = ldtab(tab, s[u], c4);
            acc.x = fmaf(nv[u], xv.x, acc.x); acc.y = fmaf(nv[u], xv.y, acc.y);
            acc.z = fmaf(nv[u], xv.z, acc.z); acc.w = fmaf(nv[u], xv.w, acc.w);
        }
    }
    for (; j + 8 <= cnt; j += 8) {
        int s[2]; float nv[2];
#pragma unroll
        for (int u = 0; u < 2; ++u) {
            unsigned p = pck[start + j + 4 * u + q];
            s[u] = (int)(p & 0xFFFFu);
            nv[u] = unpack_n(p);
        }
#pragma unroll
        for (int u = 0; u < 2; ++u) {
            float4 xv = ldtab(tab, s[u], c4);
            acc.x = fmaf(nv[u], xv.x, acc.x); acc.y = fmaf(nv[u], xv.y, acc.y);
            acc.z = fmaf(nv[u], xv.z, acc.z); acc.w = fmaf(nv[u], xv.w, acc.w);
        }
    }
    for (; j < cnt; j += 4) {
        int jj = j + q;
        bool valid = jj < cnt;
        unsigned p = pck[start + (valid ? jj : 0)];
        int s = (int)(p & 0xFFFFu);
        float nv = valid ? unpack_n(p) : 0.0f;
        float4 xv = ldtab(tab, s, c4);
        acc.x = fmaf(nv, xv.x, acc.x); acc.y = fmaf(nv, xv.y, acc.y);
        acc.z = fmaf(nv, xv.z, acc.z); acc.w = fmaf(nv, xv.w, acc.w);
    }
    acc.x += __shfl_xor(acc.x, 16); acc.y += __shfl_xor(acc.y, 16);
    acc.z += __shfl_xor(acc.z, 16); acc.w += __shfl_xor(acc.w, 16);
    acc.x += __shfl_xor(acc.x, 32); acc.y += __shfl_xor(acc.y, 32);
    acc.z += __shfl_xor(acc.z, 32); acc.w += __shfl_xor(acc.w, 32);
    if (q == 0) {
        if (bias) {
            float4 bv = *(const float4*)&bias[c4];
            acc.x += bv.x; acc.y += bv.y; acc.z += bv.z; acc.w += bv.w;
        }
        if (do_relu) {
            acc.x = fmaxf(acc.x, 0.f); acc.y = fmaxf(acc.y, 0.f);
            acc.z = fmaxf(acc.z, 0.f); acc.w = fmaxf(acc.w, 0.f);
        }
        uint2 o;
        o.x = bf16_rne(acc.x) | (bf16_rne(acc.y) << 16);
        o.y = bf16_rne(acc.z) | (bf16_rne(acc.w) << 16);
        *(uint2*)&outv[((size_t)node << 6) + c4] = o;
    }
}

// ---------------- pool over bf16 Z (+ per-graph node count): batch sorted ----------------
__global__ void pool_seg(const unsigned short* __restrict__ h, const int* __restrict__ batch,
                         float* __restrict__ pool, float* __restrict__ cntg) {
    int ch = threadIdx.x & 63;
    int grp = threadIdx.x >> 6;
    int base = (blockIdx.x * 4 + grp) * 16;
    float acc = 0.0f;
    int curg = -1, runlen = 0;
    for (int n = 0; n < 16; ++n) {
        int node = base + n;
        if (node >= N_NODES) break;
        int g = batch[node];
        float v = __uint_as_float(((unsigned)h[((size_t)node << 6) + ch]) << 16);
        if (g != curg) {
            if (curg >= 0) {
                atomicAdd(&pool[curg * 64 + ch], acc);
                if (ch == 0) atomicAdd(&cntg[curg], (float)runlen);
            }
            curg = g; acc = v; runlen = 1;
        } else { acc += v; runlen++; }
    }
    if (curg >= 0) {
        atomicAdd(&pool[curg * 64 + ch], acc);
        if (ch == 0) atomicAdd(&cntg[curg], (float)runlen);
    }
}

// ---------------- tiny output GEMM: out = P @ W3 + cnt_g * b3 ----------------
__global__ void out_gemm(const float* __restrict__ P, const float* __restrict__ cntg,
                         const float* __restrict__ W, const float* __restrict__ b,
                         float* __restrict__ out) {
    __shared__ float Ws[64 * 64];
    int tid = threadIdx.x;
    for (int i = tid; i < 64 * 64; i += 256) Ws[i] = W[i];
    __syncthreads();
    int lane = tid & 63;
    int g = blockIdx.x * 4 + (tid >> 6);
    if (g >= N_GRAPHS) return;
    float pv = P[g * 64 + lane];
    float acc = 0.0f;
#pragma unroll
    for (int k = 0; k < 64; ++k)
        acc = fmaf(__shfl(pv, k, 64), Ws[k * 64 + lane], acc);
    out[g * 64 + lane] = acc + cntg[g] * b[lane];
}

extern "C" void kernel_launch(void* const* d_in, const int* in_sizes, int n_in,
                              void* d_out, int out_size, void* d_ws, size_t ws_size,
                              hipStream_t stream) {
    const float* x   = (const float*)d_in[0];
    const int* ei    = (const int*)d_in[1];   // int32 [2, N_EDGES]
    const int* batch = (const int*)d_in[2];   // int32 [N_NODES]
    const float* W1  = (const float*)d_in[3];
    const float* b1  = (const float*)d_in[4];
    const float* W2  = (const float*)d_in[5];
    const float* b2  = (const float*)d_in[6];
    const float* W3  = (const float*)d_in[7];
    const float* b3  = (const float*)d_in[8];
    float* out = (float*)d_out;

    // workspace layout (bytes), total ~37.1MB; PCK/COL/EBUF sized for NPAD=903168
    char* ws = (char*)d_ws;
    float*    dinv = (float*)(ws);                   // 50048 f32   -> ends   200192
    int*      DEG  = (int*)(ws + 200192);            // 50048 i32   -> ends   400384
    int*      ROWP = (int*)(ws + 400384);            // 50048 i32   -> ends   600576
    int*      COL  = (int*)(ws + 600576);            // NPAD i32    -> ends  4213248
    unsigned* PCK  = (unsigned*)(ws + 4213248);      // NPAD u32    -> ends  7825920
    float*    XW   = (float*)(ws + 7825920);         // 12.8MB      -> ends 20625920
    float*    ACC  = (float*)(ws + 20625920);        // 12.8MB      -> ends 33425920
    float*    POOL = (float*)(ws + 33425920);        // 16384 f32   -> ends 33491456
    float*    CNT  = (float*)(ws + 33491456);        // 256 f32 (contiguous after POOL)
    int*      GCUR = (int*)(ws + 33492480);          // 196 i32
    unsigned* EBUF = (unsigned*)(ws + 33493504);     // NPAD u32    -> ends 37106176

    const int WAVE_NODE_BLK = N_NODES / 4;           // 12500 (exact)

    // ---- init bucket cursors
    init_k<<<1, 256, 0, stream>>>(GCUR);

    // ---- fused: edge bin-scatter (391 blks) || gemm1 x@W1->XW1 bf16 (1563 blks)
    gemm1_scatter<<<SCAT_BLK + GEMM_BLK, 256, 0, stream>>>(
        x, W1, (unsigned short*)XW, ei, GCUR, EBUF);

    // ---- per-bucket CSR finalize (+ POOL/CNT zero)
    csr_bucket<<<NBUCK, 256, 0, stream>>>(EBUF, GCUR, DEG, ROWP, dinv, COL, POOL);

    // ---- fused layer-1 agg + gemm2 (LDS-free): XW1 -> (H1 regs) -> XW2(bf16) in ACC
    agg1_gemm2<<<WAVE_NODE_BLK, 256, 0, stream>>>(ROWP, DEG, COL, dinv, PCK,
        (const unsigned short*)XW, b1, W2, (unsigned short*)ACC);

    // ---- layer 2 agg: XW2 -> H2(bf16) in XW
    agg_v4<<<WAVE_NODE_BLK, 256, 0, stream>>>(ROWP, DEG, dinv, PCK,
        (const unsigned short*)ACC, b2, (unsigned short*)XW, 1);

    // ---- layer 3 (reordered): Z = A_hat H2 -> bf16 in ACC -> pool -> small GEMM
    agg_v4<<<WAVE_NODE_BLK, 256, 0, stream>>>(ROWP, DEG, dinv, PCK,
        (const unsigned short*)XW, nullptr, (unsigned short*)ACC, 0);
    pool_seg<<<(N_NODES + 63) / 64, 256, 0, stream>>>((const unsigned short*)ACC,
        batch, POOL, CNT);
    out_gemm<<<N_GRAPHS / 4, 256, 0, stream>>>(POOL, CNT, W3, b3, out);
}